// Round 11
// baseline (169.799 us; speedup 1.0000x reference)
//
#include <hip/hip_runtime.h>
#include <hip/hip_bf16.h>
#include <cstdint>

#define NNODE 256
#define NBT   96
#define LOG2E 1.4426950408889634f

typedef __attribute__((ext_vector_type(8))) short short8;
typedef __attribute__((ext_vector_type(4))) float f32x4;

__device__ __forceinline__ unsigned pack_bf16x2(float a, float b) {
  unsigned ua = __float_as_uint(a);
  unsigned ub = __float_as_uint(b);
  unsigned ra = (ua + 0x7FFFu + ((ua >> 16) & 1u)) >> 16;
  unsigned rb = ((ub + 0x7FFFu + ((ub >> 16) & 1u)) >> 16) << 16;
  return ra | rb;
}
__device__ __forceinline__ unsigned short bf16_rn(float a) {
  unsigned ua = __float_as_uint(a);
  return (unsigned short)((ua + 0x7FFFu + ((ua >> 16) & 1u)) >> 16);
}

// ---------------------------------------------------------------------------
// Kernel 1: merged setup. grid 1122 x 256 thr, role by blockIdx.x:
//   [0,768)    pack_mask: mb[bt][w][j] bit b = adj[bt][32w+b][j]!=0
//   [768,864)  embed-t row (tid<64 active; syncs unguarded)
//   [864,1120) embed-sp row
//   [1120,1122) prep: WoT+W2T / W1T transposes (verified round-7 code)
// All roles mutually independent -> one launch replaces three.
// ---------------------------------------------------------------------------
__global__ __launch_bounds__(256) void setup_kernel(
    const int* __restrict__ adj, unsigned* __restrict__ mb,
    const float* __restrict__ te, const float* __restrict__ se, const float* __restrict__ pe,
    const float* __restrict__ Wt, const float* __restrict__ bt_,
    const float* __restrict__ Ws, const float* __restrict__ bs_,
    const float* __restrict__ Wp, const float* __restrict__ bp_,
    const float* __restrict__ Wfc, const float* __restrict__ bfc,
    const float* __restrict__ Wout, const float* __restrict__ bout,
    const float* __restrict__ W1, const float* __restrict__ W2,
    float* __restrict__ tW, float* __restrict__ spW,
    unsigned short* __restrict__ WoT, unsigned short* __restrict__ W1T,
    unsigned short* __restrict__ W2T) {
  const int blk = blockIdx.x, tid = threadIdx.x;
  __shared__ float A[64], Bv[64], C[64], D[64];

  if (blk < 768) {
    // ---- pack_mask ----
    const int bt = blk >> 3, w = blk & 7, j = tid;
    const int* a = adj + (size_t)bt * NNODE * NNODE + (size_t)w * 32 * NNODE;
    unsigned v = 0;
#pragma unroll
    for (int b = 0; b < 32; ++b)
      v |= (a[b * NNODE + j] != 0 ? 1u : 0u) << b;
    mb[((size_t)bt * 8 + w) * 256 + j] = v;
  } else if (blk < 864) {
    // ---- embed t-chain (row = blk-768) ----
    const int row = blk - 768, j = tid & 63;
    if (tid < 64) {
      float h = bt_[j];
      for (int k = 0; k < 32; ++k) h += te[row * 32 + k] * Wt[k * 64 + j];
      A[j] = h;
    }
    __syncthreads();
    if (tid < 64) {
      float tv = bfc[j];
      for (int k = 0; k < 64; ++k) tv += A[k] * Wfc[k * 64 + j];
      Bv[j] = tv;
    }
    __syncthreads();
    if (tid < 64) {
      float tw = bout[j];
      for (int d = 0; d < 64; ++d) tw += Bv[d] * Wout[(64 + d) * 64 + j];
      tW[row * 64 + j] = tw;
    }
  } else if (blk < 1120) {
    // ---- embed sp-chain (n = blk-864) ----
    const int n = blk - 864, j = tid & 63;
    float spv = 0.f;
    if (tid < 64) {
      float sh = bs_[j], ph = bp_[j];
      for (int k = 0; k < 32; ++k) {
        sh += se[n * 32 + k] * Ws[k * 64 + j];
        ph += pe[n * 32 + k] * Wp[k * 64 + j];
      }
      A[j] = sh; Bv[j] = ph;
    }
    __syncthreads();
    if (tid < 64) {
      float sv = bfc[j], pv = bfc[j];
      for (int k = 0; k < 64; ++k) {
        sv += A[k] * Wfc[k * 64 + j];
        pv += Bv[k] * Wfc[k * 64 + j];
      }
      C[j] = sv; D[j] = pv;
    }
    __syncthreads();
    if (tid < 64) {
      spv = bout[j];
      for (int k = 0; k < 64; ++k)
        spv += C[k] * Wout[k * 64 + j] + D[k] * Wout[(64 + k) * 64 + j];
    }
    __syncthreads();
    if (tid < 64) A[j] = spv;
    __syncthreads();
    if (tid < 64) {
      float spw = 0.f;
      for (int d = 0; d < 64; ++d) spw += A[d] * Wout[(64 + d) * 64 + j];
      spW[n * 64 + j] = spw;
    }
  } else if (blk == 1120) {
    // ---- prep: WoT + W2T ----
    {
      const int c = tid >> 2, d0 = (tid & 3) * 16;
#pragma unroll
      for (int i = 0; i < 16; ++i)
        WoT[c * 64 + d0 + i] = bf16_rn(Wout[(size_t)(d0 + i) * 64 + c]);
    }
    const int k = tid;
#pragma unroll
    for (int d = 0; d < 64; ++d)
      W2T[d * 256 + k] = bf16_rn(W2[(size_t)k * 64 + d]);
  } else {
    // ---- prep: W1T ----
    const int hd = tid;
    unsigned u[32];
#pragma unroll
    for (int p = 0; p < 32; ++p) {
      float a = W1[(size_t)(2 * p) * 256 + hd];
      float b = W1[(size_t)(2 * p + 1) * 256 + hd];
      u[p] = pack_bf16x2(a, b);
    }
    unsigned* o = (unsigned*)(W1T + (size_t)hd * 64);
#pragma unroll
    for (int p = 0; p < 8; ++p) {
      uint4 v;
      v.x = u[4 * p + 0]; v.y = u[4 * p + 1];
      v.z = u[4 * p + 2]; v.w = u[4 * p + 3];
      *reinterpret_cast<uint4*>(o + 4 * p) = v;
    }
  }
}

// ---------------------------------------------------------------------------
// Kernel 2: fused feat1+agg1 (verified round 10, unchanged).
// grid (96, 4 heads, 2 j-halves), 512 thr.
// ---------------------------------------------------------------------------
__global__ __launch_bounds__(512, 2) void fused1_kernel(
    const float* __restrict__ x, const unsigned* __restrict__ W1Tu,
    const unsigned* __restrict__ mbg, const float* __restrict__ a1s,
    const float* __restrict__ a1d, const float* __restrict__ b1,
    unsigned* __restrict__ hgl) {
  const int bt = blockIdx.x, head = blockIdx.y, z = blockIdx.z, tid = threadIdx.x;
  __shared__ union U {
    unsigned xb[256][36];
    unsigned hpT[64][132];
    unsigned short ob[128][72];
  } sm;
  __shared__ unsigned w1t[64][36];
  __shared__ unsigned mbs[1024];
  __shared__ float ess[256], eds[128], asv[64], adv[64];

  if (tid < 256) {
    const float* xrow = x + ((size_t)bt * NNODE + tid) * 64;
    unsigned u[32];
#pragma unroll
    for (int p = 0; p < 16; ++p) {
      float4 v = reinterpret_cast<const float4*>(xrow)[p];
      u[2 * p] = pack_bf16x2(v.x, v.y);
      u[2 * p + 1] = pack_bf16x2(v.z, v.w);
    }
#pragma unroll
    for (int p = 0; p < 8; ++p) {
      uint4 v; v.x = u[4 * p]; v.y = u[4 * p + 1]; v.z = u[4 * p + 2]; v.w = u[4 * p + 3];
      *reinterpret_cast<uint4*>(&sm.xb[tid][4 * p]) = v;
    }
    const int w = tid >> 5, col = (tid & 31) * 4;
    *reinterpret_cast<uint4*>(&mbs[w * 128 + col]) =
        *reinterpret_cast<const uint4*>(&mbg[(size_t)bt * 2048 + w * 256 + z * 128 + col]);
  } else {
    const int tt = tid - 256;
#pragma unroll
    for (int c = 0; c < 2; ++c) {
      const int idx = tt * 2 + c;
      const int r = idx >> 3, c4 = (idx & 7) * 4;
      *reinterpret_cast<uint4*>(&w1t[r][c4]) =
          *reinterpret_cast<const uint4*>(&W1Tu[(size_t)(head * 64 + r) * 32 + c4]);
    }
    if (tt < 64) asv[tt] = a1s[head * 64 + tt];
    else if (tt < 128) adv[tt - 64] = a1d[head * 64 + (tt - 64)];
  }
  __syncthreads();

  const int lane = tid & 63, wv = tid >> 6;
  const int m = lane & 15, q = lane >> 4;
  const f32x4 z4 = {0.f, 0.f, 0.f, 0.f};

  f32x4 cf[4][2];
#pragma unroll
  for (int mt = 0; mt < 4; ++mt)
#pragma unroll
    for (int nt = 0; nt < 2; ++nt) cf[mt][nt] = z4;
#pragma unroll
  for (int kt = 0; kt < 2; ++kt) {
    short8 af[4], bf[2];
#pragma unroll
    for (int mt = 0; mt < 4; ++mt)
      af[mt] = *reinterpret_cast<const short8*>(&w1t[mt * 16 + m][kt * 16 + q * 4]);
#pragma unroll
    for (int nt = 0; nt < 2; ++nt)
      bf[nt] = *reinterpret_cast<const short8*>(&sm.xb[wv * 32 + nt * 16 + m][kt * 16 + q * 4]);
#pragma unroll
    for (int mt = 0; mt < 4; ++mt)
#pragma unroll
      for (int nt = 0; nt < 2; ++nt)
        cf[mt][nt] = __builtin_amdgcn_mfma_f32_16x16x32_bf16(af[mt], bf[nt], cf[mt][nt], 0, 0, 0);
  }
  __syncthreads();

  {
    unsigned short* hpT16 = reinterpret_cast<unsigned short*>(&sm.hpT[0][0]);
#pragma unroll
    for (int mt = 0; mt < 4; ++mt)
#pragma unroll
      for (int nt = 0; nt < 2; ++nt)
#pragma unroll
        for (int reg = 0; reg < 4; ++reg) {
          const int d = mt * 16 + q * 4 + reg;
          const int n = wv * 32 + nt * 16 + m;
          hpT16[d * 264 + n] = bf16_rn(cf[mt][nt][reg]);
        }
  }
  __syncthreads();

  if (tid < 256) {
    const int n = tid;
    const unsigned sh = (n & 1) * 16;
    float s = 0.f;
#pragma unroll 8
    for (int d = 0; d < 64; ++d) {
      unsigned u = sm.hpT[d][n >> 1];
      s += __uint_as_float((u >> sh) << 16) * asv[d];
    }
    ess[n] = s * LOG2E;
  } else if (tid < 384) {
    const int jl = tid - 256;
    const int n = z * 128 + jl;
    const unsigned sh = (n & 1) * 16;
    float s = 0.f;
#pragma unroll 8
    for (int d = 0; d < 64; ++d) {
      unsigned u = sm.hpT[d][n >> 1];
      s += __uint_as_float((u >> sh) << 16) * adv[d];
    }
    eds[jl] = s * LOG2E;
  }
  __syncthreads();

  f32x4 cacc[4], cden = z4;
#pragma unroll
  for (int nt = 0; nt < 4; ++nt) cacc[nt] = z4;
  const float edv = eds[wv * 16 + m];
  const short8 ones8 = {(short)0x3F80, (short)0x3F80, (short)0x3F80, (short)0x3F80,
                        (short)0x3F80, (short)0x3F80, (short)0x3F80, (short)0x3F80};

  for (int kt = 0; kt < 8; ++kt) {
    short8 bfr[4];
#pragma unroll
    for (int nt = 0; nt < 4; ++nt)
      bfr[nt] = *reinterpret_cast<const short8*>(&sm.hpT[nt * 16 + m][kt * 16 + q * 4]);
    float e[8];
    *reinterpret_cast<float4*>(&e[0]) = *reinterpret_cast<const float4*>(&ess[kt * 32 + q * 8]);
    *reinterpret_cast<float4*>(&e[4]) = *reinterpret_cast<const float4*>(&ess[kt * 32 + q * 8 + 4]);
    const unsigned bits = mbs[kt * 128 + wv * 16 + m] >> (q * 8);
    float pv[8];
#pragma unroll
    for (int r = 0; r < 8; ++r) {
      float sc = e[r] + edv;
      sc = fmaxf(sc, 0.2f * sc);
      pv[r] = ((bits >> r) & 1u) ? exp2f(sc) : 0.f;
    }
    union { unsigned u[4]; short8 s; } A;
#pragma unroll
    for (int h = 0; h < 4; ++h) A.u[h] = pack_bf16x2(pv[2 * h], pv[2 * h + 1]);
#pragma unroll
    for (int nt = 0; nt < 4; ++nt)
      cacc[nt] = __builtin_amdgcn_mfma_f32_16x16x32_bf16(A.s, bfr[nt], cacc[nt], 0, 0, 0);
    cden = __builtin_amdgcn_mfma_f32_16x16x32_bf16(A.s, ones8, cden, 0, 0, 0);
  }
  __syncthreads();

  float b1v[4];
#pragma unroll
  for (int nt = 0; nt < 4; ++nt) b1v[nt] = b1[head * 64 + nt * 16 + m];
#pragma unroll
  for (int reg = 0; reg < 4; ++reg) {
    const int jl = wv * 16 + q * 4 + reg;
    const float inv = 1.f / fmaxf(cden[reg], 1e-30f);
#pragma unroll
    for (int nt = 0; nt < 4; ++nt) {
      float v = cacc[nt][reg] * inv + b1v[nt];
      v = v > 0.f ? v : expm1f(v);
      sm.ob[jl][nt * 16 + m] = bf16_rn(v);
    }
  }
  __syncthreads();

  unsigned* go = hgl + (size_t)bt * 32768 + (size_t)z * 128 * 128 + head * 32;
#pragma unroll
  for (int c = 0; c < 2; ++c) {
    const int idx = tid * 2 + c;
    const int jl = idx >> 3, c4 = (idx & 7) * 4;
    *reinterpret_cast<uint4*>(&go[(size_t)jl * 128 + c4]) =
        *reinterpret_cast<const uint4*>(&sm.ob[jl][c4 * 2]);
  }
}

// ---------------------------------------------------------------------------
// Kernel 3 (NEW): fused feat2+agg2. grid (96, 2 j-halves), 512 thr.
// Phase A: hp2[64 d][256 n] = W2T @ h, K=256 in 4 chunks of 64 (VGPR accum,
//          chunk order == feat2's kt order -> bit-identical). -> LDS hpT.
// Phase B: es/ed, masked-softmax MFMA agg, od@WoT + spW + tW epilogue
//          (agg2's verified code verbatim).
// ---------------------------------------------------------------------------
__global__ __launch_bounds__(512, 2) void fused2_kernel(
    const unsigned* __restrict__ hglu, const unsigned* __restrict__ W2Tu,
    const unsigned* __restrict__ mbg, const float* __restrict__ a2s,
    const float* __restrict__ a2d, const float* __restrict__ b2,
    const unsigned* __restrict__ WoTu, const float* __restrict__ spW,
    const float* __restrict__ tW, float* __restrict__ out) {
  const int bt = blockIdx.x, jh = blockIdx.y, tid = threadIdx.x;
  const int jbase = jh * 128;
  __shared__ union U {
    struct { unsigned h_c[256][36]; unsigned w2t_c[64][36]; } fs;  // 46080 B
    unsigned hpT[64][132];                                         // 33792 B
    unsigned short ob[128][72];                                    // 18432 B
  } sm;
  __shared__ unsigned wol[64][36];
  __shared__ unsigned mbs[1024];
  __shared__ float ess[256], eds[128];
  __shared__ float a2sv[64], a2dv[64];

  // persistent staging (disjoint regions; ordered by first kc sync)
  {
    int row = tid >> 3, col = (tid & 7) * 4;
    *reinterpret_cast<uint4*>(&wol[row][col]) =
        *reinterpret_cast<const uint4*>(&WoTu[row * 32 + col]);
  }
  if (tid < 256) {
    int w = tid >> 5, col = (tid & 31) * 4;
    *reinterpret_cast<uint4*>(&mbs[w * 128 + col]) =
        *reinterpret_cast<const uint4*>(&mbg[(size_t)bt * 2048 + w * 256 + jbase + col]);
  }
  if (tid >= 384 && tid < 448) a2sv[tid - 384] = a2s[tid - 384];
  else if (tid >= 448) a2dv[tid - 448] = a2d[tid - 448];

  const int lane = tid & 63, wv = tid >> 6;
  const int m = lane & 15, q = lane >> 4;
  const f32x4 z4 = {0.f, 0.f, 0.f, 0.f};

  // ---- Phase A: feat MFMA, wave wv covers n in [wv*32, +32) ----
  f32x4 cf[4][2];
#pragma unroll
  for (int mt = 0; mt < 4; ++mt)
#pragma unroll
    for (int nt = 0; nt < 2; ++nt) cf[mt][nt] = z4;

  for (int kc = 0; kc < 4; ++kc) {
    __syncthreads();   // prior chunk's LDS reads (or persistent staging) done
#pragma unroll
    for (int c = 0; c < 4; ++c) {
      int i4 = tid + c * 512;
      int n = i4 >> 3, col = (i4 & 7) * 4;
      *reinterpret_cast<uint4*>(&sm.fs.h_c[n][col]) =
          *reinterpret_cast<const uint4*>(&hglu[(size_t)bt * 32768 + n * 128 + kc * 32 + col]);
    }
    {
      int d = tid >> 3, col = (tid & 7) * 4;
      *reinterpret_cast<uint4*>(&sm.fs.w2t_c[d][col]) =
          *reinterpret_cast<const uint4*>(&W2Tu[d * 128 + kc * 32 + col]);
    }
    __syncthreads();
#pragma unroll
    for (int kt2 = 0; kt2 < 2; ++kt2) {
      short8 af[4], bf[2];
#pragma unroll
      for (int mt = 0; mt < 4; ++mt)
        af[mt] = *reinterpret_cast<const short8*>(&sm.fs.w2t_c[mt * 16 + m][kt2 * 16 + q * 4]);
#pragma unroll
      for (int nt = 0; nt < 2; ++nt)
        bf[nt] = *reinterpret_cast<const short8*>(&sm.fs.h_c[wv * 32 + nt * 16 + m][kt2 * 16 + q * 4]);
#pragma unroll
      for (int mt = 0; mt < 4; ++mt)
#pragma unroll
        for (int nt = 0; nt < 2; ++nt)
          cf[mt][nt] = __builtin_amdgcn_mfma_f32_16x16x32_bf16(af[mt], bf[nt], cf[mt][nt], 0, 0, 0);
    }
  }
  __syncthreads();   // last chunk reads done; fs dead -> hpT overlay safe

  {
    unsigned short* hpT16 = reinterpret_cast<unsigned short*>(&sm.hpT[0][0]);
#pragma unroll
    for (int mt = 0; mt < 4; ++mt)
#pragma unroll
      for (int nt = 0; nt < 2; ++nt)
#pragma unroll
        for (int reg = 0; reg < 4; ++reg) {
          const int d = mt * 16 + q * 4 + reg;
          const int n = wv * 32 + nt * 16 + m;
          hpT16[d * 264 + n] = bf16_rn(cf[mt][nt][reg]);
        }
  }
  __syncthreads();

  // ---- es (all i) / ed (this j-half) ----
  if (tid < 256) {
    const int n = tid;
    const unsigned sh = (n & 1) * 16;
    float s = 0.f;
#pragma unroll 8
    for (int d = 0; d < 64; ++d) {
      unsigned u = sm.hpT[d][n >> 1];
      s += __uint_as_float((u >> sh) << 16) * a2sv[d];
    }
    ess[n] = s * LOG2E;
  } else if (tid < 384) {
    const int jl = tid - 256;
    const int n = jbase + jl;
    const unsigned sh = (n & 1) * 16;
    float s = 0.f;
#pragma unroll 8
    for (int d = 0; d < 64; ++d) {
      unsigned u = sm.hpT[d][n >> 1];
      s += __uint_as_float((u >> sh) << 16) * a2dv[d];
    }
    eds[jl] = s * LOG2E;
  }
  __syncthreads();

  // ---- agg: wave owns 16 j-rows ----
  f32x4 cacc[4], cden = z4;
#pragma unroll
  for (int nt = 0; nt < 4; ++nt) cacc[nt] = z4;
  const float edv = eds[wv * 16 + m];
  const short8 ones8 = {(short)0x3F80, (short)0x3F80, (short)0x3F80, (short)0x3F80,
                        (short)0x3F80, (short)0x3F80, (short)0x3F80, (short)0x3F80};

  for (int kt = 0; kt < 8; ++kt) {
    short8 bfr[4];
#pragma unroll
    for (int nt = 0; nt < 4; ++nt)
      bfr[nt] = *reinterpret_cast<const short8*>(&sm.hpT[nt * 16 + m][kt * 16 + q * 4]);
    float e[8];
    *reinterpret_cast<float4*>(&e[0]) = *reinterpret_cast<const float4*>(&ess[kt * 32 + q * 8]);
    *reinterpret_cast<float4*>(&e[4]) = *reinterpret_cast<const float4*>(&ess[kt * 32 + q * 8 + 4]);
    const unsigned bits = mbs[kt * 128 + wv * 16 + m] >> (q * 8);
    float pv[8];
#pragma unroll
    for (int r = 0; r < 8; ++r) {
      float sc = e[r] + edv;
      sc = fmaxf(sc, 0.2f * sc);
      pv[r] = ((bits >> r) & 1u) ? exp2f(sc) : 0.f;
    }
    union { unsigned u[4]; short8 s; } A;
#pragma unroll
    for (int h = 0; h < 4; ++h) A.u[h] = pack_bf16x2(pv[2 * h], pv[2 * h + 1]);
#pragma unroll
    for (int nt = 0; nt < 4; ++nt)
      cacc[nt] = __builtin_amdgcn_mfma_f32_16x16x32_bf16(A.s, bfr[nt], cacc[nt], 0, 0, 0);
    cden = __builtin_amdgcn_mfma_f32_16x16x32_bf16(A.s, ones8, cden, 0, 0, 0);
  }
  __syncthreads();   // hpT dead -> ob overlay safe

  float b2v[4];
#pragma unroll
  for (int nt = 0; nt < 4; ++nt) b2v[nt] = b2[nt * 16 + m];
#pragma unroll
  for (int reg = 0; reg < 4; ++reg) {
    const int jl = wv * 16 + q * 4 + reg;
    const float inv = 1.f / fmaxf(cden[reg], 1e-30f);
#pragma unroll
    for (int nt = 0; nt < 4; ++nt)
      sm.ob[jl][nt * 16 + m] = bf16_rn(cacc[nt][reg] * inv + b2v[nt]);
  }
  __syncthreads();

  // ---- epilogue: out = od @ Wout[0:64] + spW + tW ----
  f32x4 c2[4];
#pragma unroll
  for (int ct = 0; ct < 4; ++ct) c2[ct] = z4;
#pragma unroll
  for (int kt2 = 0; kt2 < 2; ++kt2) {
    short8 a2f = *reinterpret_cast<const short8*>(&sm.ob[wv * 16 + m][kt2 * 32 + q * 8]);
#pragma unroll
    for (int ct = 0; ct < 4; ++ct) {
      short8 bw = *reinterpret_cast<const short8*>(&wol[ct * 16 + m][kt2 * 16 + q * 4]);
      c2[ct] = __builtin_amdgcn_mfma_f32_16x16x32_bf16(a2f, bw, c2[ct], 0, 0, 0);
    }
  }
  float tWv[4];
#pragma unroll
  for (int ct = 0; ct < 4; ++ct) tWv[ct] = tW[bt * 64 + ct * 16 + m];
#pragma unroll
  for (int reg = 0; reg < 4; ++reg) {
    const int j = jbase + wv * 16 + q * 4 + reg;
#pragma unroll
    for (int ct = 0; ct < 4; ++ct) {
      const int cc = ct * 16 + m;
      out[((size_t)bt * NNODE + j) * 64 + cc] =
          c2[ct][reg] + spW[j * 64 + cc] + tWv[ct];
    }
  }
}

// ---------------------------------------------------------------------------
extern "C" void kernel_launch(void* const* d_in, const int* in_sizes, int n_in,
                              void* d_out, int out_size, void* d_ws, size_t ws_size,
                              hipStream_t stream) {
  const float* x    = (const float*)d_in[0];
  const int*   adj  = (const int*)d_in[1];
  const float* te   = (const float*)d_in[2];
  const float* se   = (const float*)d_in[3];
  const float* pe   = (const float*)d_in[4];
  const float* Wt   = (const float*)d_in[5];
  const float* bt_  = (const float*)d_in[6];
  const float* Ws   = (const float*)d_in[7];
  const float* bs_  = (const float*)d_in[8];
  const float* Wp   = (const float*)d_in[9];
  const float* bp_  = (const float*)d_in[10];
  const float* Wfc  = (const float*)d_in[11];
  const float* bfc  = (const float*)d_in[12];
  const float* Wout = (const float*)d_in[13];
  const float* bout = (const float*)d_in[14];
  const float* W1   = (const float*)d_in[15];
  const float* b1   = (const float*)d_in[16];
  const float* a1s  = (const float*)d_in[17];
  const float* a1d  = (const float*)d_in[18];
  const float* W2   = (const float*)d_in[19];
  const float* b2   = (const float*)d_in[20];
  const float* a2s  = (const float*)d_in[21];
  const float* a2d  = (const float*)d_in[22];

  // workspace layout (offsets preserved from rounds 7-10)
  char* ws = (char*)d_ws;
  unsigned*       mb   = (unsigned*)(ws);                  // 786432
  float*          tW   = (float*)(ws + 786432);            // 24576
  float*          spW  = (float*)(ws + 811008);            // 65536
  unsigned short* WoT  = (unsigned short*)(ws + 876544);   // 8192
  unsigned short* W1T  = (unsigned short*)(ws + 884736);   // 32768
  unsigned short* W2T  = (unsigned short*)(ws + 917504);   // 32768
  unsigned*       hgl  = (unsigned*)(ws + 13533184);       // 12582912

  setup_kernel<<<1122, 256, 0, stream>>>(adj, mb, te, se, pe, Wt, bt_, Ws, bs_,
                                         Wp, bp_, Wfc, bfc, Wout, bout, W1, W2,
                                         tW, spW, WoT, W1T, W2T);
  fused1_kernel<<<dim3(NBT, 4, 2), 512, 0, stream>>>(x, (const unsigned*)W1T, mb,
                                                     a1s, a1d, b1, hgl);
  fused2_kernel<<<dim3(NBT, 2), 512, 0, stream>>>(hgl, (const unsigned*)W2T, mb,
                                                  a2s, a2d, b2, (const unsigned*)WoT,
                                                  spW, tW, (float*)d_out);
}

// Round 12
// 168.521 us; speedup vs baseline: 1.0076x; 1.0076x over previous
//
#include <hip/hip_runtime.h>
#include <hip/hip_bf16.h>
#include <cstdint>

#define NNODE 256
#define NBT   96
#define LOG2E 1.4426950408889634f

typedef __attribute__((ext_vector_type(8))) short short8;
typedef __attribute__((ext_vector_type(4))) float f32x4;

__device__ __forceinline__ unsigned pack_bf16x2(float a, float b) {
  unsigned ua = __float_as_uint(a);
  unsigned ub = __float_as_uint(b);
  unsigned ra = (ua + 0x7FFFu + ((ua >> 16) & 1u)) >> 16;
  unsigned rb = ((ub + 0x7FFFu + ((ub >> 16) & 1u)) >> 16) << 16;
  return ra | rb;
}
__device__ __forceinline__ unsigned short bf16_rn(float a) {
  unsigned ua = __float_as_uint(a);
  return (unsigned short)((ua + 0x7FFFu + ((ua >> 16) & 1u)) >> 16);
}

// ---------------------------------------------------------------------------
// Kernel 1: merged setup (verified round 11, unchanged).
// ---------------------------------------------------------------------------
__global__ __launch_bounds__(256) void setup_kernel(
    const int* __restrict__ adj, unsigned* __restrict__ mb,
    const float* __restrict__ te, const float* __restrict__ se, const float* __restrict__ pe,
    const float* __restrict__ Wt, const float* __restrict__ bt_,
    const float* __restrict__ Ws, const float* __restrict__ bs_,
    const float* __restrict__ Wp, const float* __restrict__ bp_,
    const float* __restrict__ Wfc, const float* __restrict__ bfc,
    const float* __restrict__ Wout, const float* __restrict__ bout,
    const float* __restrict__ W1, const float* __restrict__ W2,
    float* __restrict__ tW, float* __restrict__ spW,
    unsigned short* __restrict__ WoT, unsigned short* __restrict__ W1T,
    unsigned short* __restrict__ W2T) {
  const int blk = blockIdx.x, tid = threadIdx.x;
  __shared__ float A[64], Bv[64], C[64], D[64];

  if (blk < 768) {
    const int bt = blk >> 3, w = blk & 7, j = tid;
    const int* a = adj + (size_t)bt * NNODE * NNODE + (size_t)w * 32 * NNODE;
    unsigned v = 0;
#pragma unroll
    for (int b = 0; b < 32; ++b)
      v |= (a[b * NNODE + j] != 0 ? 1u : 0u) << b;
    mb[((size_t)bt * 8 + w) * 256 + j] = v;
  } else if (blk < 864) {
    const int row = blk - 768, j = tid & 63;
    if (tid < 64) {
      float h = bt_[j];
      for (int k = 0; k < 32; ++k) h += te[row * 32 + k] * Wt[k * 64 + j];
      A[j] = h;
    }
    __syncthreads();
    if (tid < 64) {
      float tv = bfc[j];
      for (int k = 0; k < 64; ++k) tv += A[k] * Wfc[k * 64 + j];
      Bv[j] = tv;
    }
    __syncthreads();
    if (tid < 64) {
      float tw = bout[j];
      for (int d = 0; d < 64; ++d) tw += Bv[d] * Wout[(64 + d) * 64 + j];
      tW[row * 64 + j] = tw;
    }
  } else if (blk < 1120) {
    const int n = blk - 864, j = tid & 63;
    float spv = 0.f;
    if (tid < 64) {
      float sh = bs_[j], ph = bp_[j];
      for (int k = 0; k < 32; ++k) {
        sh += se[n * 32 + k] * Ws[k * 64 + j];
        ph += pe[n * 32 + k] * Wp[k * 64 + j];
      }
      A[j] = sh; Bv[j] = ph;
    }
    __syncthreads();
    if (tid < 64) {
      float sv = bfc[j], pv = bfc[j];
      for (int k = 0; k < 64; ++k) {
        sv += A[k] * Wfc[k * 64 + j];
        pv += Bv[k] * Wfc[k * 64 + j];
      }
      C[j] = sv; D[j] = pv;
    }
    __syncthreads();
    if (tid < 64) {
      spv = bout[j];
      for (int k = 0; k < 64; ++k)
        spv += C[k] * Wout[k * 64 + j] + D[k] * Wout[(64 + k) * 64 + j];
    }
    __syncthreads();
    if (tid < 64) A[j] = spv;
    __syncthreads();
    if (tid < 64) {
      float spw = 0.f;
      for (int d = 0; d < 64; ++d) spw += A[d] * Wout[(64 + d) * 64 + j];
      spW[n * 64 + j] = spw;
    }
  } else if (blk == 1120) {
    {
      const int c = tid >> 2, d0 = (tid & 3) * 16;
#pragma unroll
      for (int i = 0; i < 16; ++i)
        WoT[c * 64 + d0 + i] = bf16_rn(Wout[(size_t)(d0 + i) * 64 + c]);
    }
    const int k = tid;
#pragma unroll
    for (int d = 0; d < 64; ++d)
      W2T[d * 256 + k] = bf16_rn(W2[(size_t)k * 64 + d]);
  } else {
    const int hd = tid;
    unsigned u[32];
#pragma unroll
    for (int p = 0; p < 32; ++p) {
      float a = W1[(size_t)(2 * p) * 256 + hd];
      float b = W1[(size_t)(2 * p + 1) * 256 + hd];
      u[p] = pack_bf16x2(a, b);
    }
    unsigned* o = (unsigned*)(W1T + (size_t)hd * 64);
#pragma unroll
    for (int p = 0; p < 8; ++p) {
      uint4 v;
      v.x = u[4 * p + 0]; v.y = u[4 * p + 1];
      v.z = u[4 * p + 2]; v.w = u[4 * p + 3];
      *reinterpret_cast<uint4*>(o + 4 * p) = v;
    }
  }
}

// ---------------------------------------------------------------------------
// Kernel 2: fused feat1+agg1. grid (96,4,2), 512 thr.
// CHANGE (r12): es/ed computed from f32 cf registers + shfl_xor q-reduction
// (replaces serial 64-iter LDS loop + one barrier).
// ---------------------------------------------------------------------------
__global__ __launch_bounds__(512, 2) void fused1_kernel(
    const float* __restrict__ x, const unsigned* __restrict__ W1Tu,
    const unsigned* __restrict__ mbg, const float* __restrict__ a1s,
    const float* __restrict__ a1d, const float* __restrict__ b1,
    unsigned* __restrict__ hgl) {
  const int bt = blockIdx.x, head = blockIdx.y, z = blockIdx.z, tid = threadIdx.x;
  __shared__ union U {
    unsigned xb[256][36];
    unsigned hpT[64][132];
    unsigned short ob[128][72];
  } sm;
  __shared__ unsigned w1t[64][36];
  __shared__ unsigned mbs[1024];
  __shared__ float ess[256], eds[128], asv[64], adv[64];

  if (tid < 256) {
    const float* xrow = x + ((size_t)bt * NNODE + tid) * 64;
    unsigned u[32];
#pragma unroll
    for (int p = 0; p < 16; ++p) {
      float4 v = reinterpret_cast<const float4*>(xrow)[p];
      u[2 * p] = pack_bf16x2(v.x, v.y);
      u[2 * p + 1] = pack_bf16x2(v.z, v.w);
    }
#pragma unroll
    for (int p = 0; p < 8; ++p) {
      uint4 v; v.x = u[4 * p]; v.y = u[4 * p + 1]; v.z = u[4 * p + 2]; v.w = u[4 * p + 3];
      *reinterpret_cast<uint4*>(&sm.xb[tid][4 * p]) = v;
    }
    const int w = tid >> 5, col = (tid & 31) * 4;
    *reinterpret_cast<uint4*>(&mbs[w * 128 + col]) =
        *reinterpret_cast<const uint4*>(&mbg[(size_t)bt * 2048 + w * 256 + z * 128 + col]);
  } else {
    const int tt = tid - 256;
#pragma unroll
    for (int c = 0; c < 2; ++c) {
      const int idx = tt * 2 + c;
      const int r = idx >> 3, c4 = (idx & 7) * 4;
      *reinterpret_cast<uint4*>(&w1t[r][c4]) =
          *reinterpret_cast<const uint4*>(&W1Tu[(size_t)(head * 64 + r) * 32 + c4]);
    }
    if (tt < 64) asv[tt] = a1s[head * 64 + tt];
    else if (tt < 128) adv[tt - 64] = a1d[head * 64 + (tt - 64)];
  }
  __syncthreads();

  const int lane = tid & 63, wv = tid >> 6;
  const int m = lane & 15, q = lane >> 4;
  const f32x4 z4 = {0.f, 0.f, 0.f, 0.f};

  f32x4 cf[4][2];
#pragma unroll
  for (int mt = 0; mt < 4; ++mt)
#pragma unroll
    for (int nt = 0; nt < 2; ++nt) cf[mt][nt] = z4;
#pragma unroll
  for (int kt = 0; kt < 2; ++kt) {
    short8 af[4], bf[2];
#pragma unroll
    for (int mt = 0; mt < 4; ++mt)
      af[mt] = *reinterpret_cast<const short8*>(&w1t[mt * 16 + m][kt * 16 + q * 4]);
#pragma unroll
    for (int nt = 0; nt < 2; ++nt)
      bf[nt] = *reinterpret_cast<const short8*>(&sm.xb[wv * 32 + nt * 16 + m][kt * 16 + q * 4]);
#pragma unroll
    for (int mt = 0; mt < 4; ++mt)
#pragma unroll
      for (int nt = 0; nt < 2; ++nt)
        cf[mt][nt] = __builtin_amdgcn_mfma_f32_16x16x32_bf16(af[mt], bf[nt], cf[mt][nt], 0, 0, 0);
  }
  __syncthreads();   // xb dead; hpT overlay safe

  // ---- es/ed from cf registers: partial over this thread's 16 d, then q-reduce
  {
    float pes0 = 0.f, pes1 = 0.f, ped0 = 0.f, ped1 = 0.f;
#pragma unroll
    for (int mt = 0; mt < 4; ++mt)
#pragma unroll
      for (int reg = 0; reg < 4; ++reg) {
        const int d = mt * 16 + q * 4 + reg;
        const float a = asv[d], bdv = adv[d];
        pes0 += cf[mt][0][reg] * a;  ped0 += cf[mt][0][reg] * bdv;
        pes1 += cf[mt][1][reg] * a;  ped1 += cf[mt][1][reg] * bdv;
      }
    pes0 += __shfl_xor(pes0, 16, 64); pes0 += __shfl_xor(pes0, 32, 64);
    pes1 += __shfl_xor(pes1, 16, 64); pes1 += __shfl_xor(pes1, 32, 64);
    ped0 += __shfl_xor(ped0, 16, 64); ped0 += __shfl_xor(ped0, 32, 64);
    ped1 += __shfl_xor(ped1, 16, 64); ped1 += __shfl_xor(ped1, 32, 64);
    if (q == 0) {
      const int n0 = wv * 32 + m, n1 = wv * 32 + 16 + m;
      ess[n0] = pes0 * LOG2E;
      ess[n1] = pes1 * LOG2E;
      if ((n0 >> 7) == z) eds[n0 & 127] = ped0 * LOG2E;
      if ((n1 >> 7) == z) eds[n1 & 127] = ped1 * LOG2E;
    }
  }

  {
    unsigned short* hpT16 = reinterpret_cast<unsigned short*>(&sm.hpT[0][0]);
#pragma unroll
    for (int mt = 0; mt < 4; ++mt)
#pragma unroll
      for (int nt = 0; nt < 2; ++nt)
#pragma unroll
        for (int reg = 0; reg < 4; ++reg) {
          const int d = mt * 16 + q * 4 + reg;
          const int n = wv * 32 + nt * 16 + m;
          hpT16[d * 264 + n] = bf16_rn(cf[mt][nt][reg]);
        }
  }
  __syncthreads();

  f32x4 cacc[4], cden = z4;
#pragma unroll
  for (int nt = 0; nt < 4; ++nt) cacc[nt] = z4;
  const float edv = eds[wv * 16 + m];
  const short8 ones8 = {(short)0x3F80, (short)0x3F80, (short)0x3F80, (short)0x3F80,
                        (short)0x3F80, (short)0x3F80, (short)0x3F80, (short)0x3F80};

  for (int kt = 0; kt < 8; ++kt) {
    short8 bfr[4];
#pragma unroll
    for (int nt = 0; nt < 4; ++nt)
      bfr[nt] = *reinterpret_cast<const short8*>(&sm.hpT[nt * 16 + m][kt * 16 + q * 4]);
    float e[8];
    *reinterpret_cast<float4*>(&e[0]) = *reinterpret_cast<const float4*>(&ess[kt * 32 + q * 8]);
    *reinterpret_cast<float4*>(&e[4]) = *reinterpret_cast<const float4*>(&ess[kt * 32 + q * 8 + 4]);
    const unsigned bits = mbs[kt * 128 + wv * 16 + m] >> (q * 8);
    float pv[8];
#pragma unroll
    for (int r = 0; r < 8; ++r) {
      float sc = e[r] + edv;
      sc = fmaxf(sc, 0.2f * sc);
      pv[r] = ((bits >> r) & 1u) ? exp2f(sc) : 0.f;
    }
    union { unsigned u[4]; short8 s; } A;
#pragma unroll
    for (int h = 0; h < 4; ++h) A.u[h] = pack_bf16x2(pv[2 * h], pv[2 * h + 1]);
#pragma unroll
    for (int nt = 0; nt < 4; ++nt)
      cacc[nt] = __builtin_amdgcn_mfma_f32_16x16x32_bf16(A.s, bfr[nt], cacc[nt], 0, 0, 0);
    cden = __builtin_amdgcn_mfma_f32_16x16x32_bf16(A.s, ones8, cden, 0, 0, 0);
  }
  __syncthreads();

  float b1v[4];
#pragma unroll
  for (int nt = 0; nt < 4; ++nt) b1v[nt] = b1[head * 64 + nt * 16 + m];
#pragma unroll
  for (int reg = 0; reg < 4; ++reg) {
    const int jl = wv * 16 + q * 4 + reg;
    const float inv = 1.f / fmaxf(cden[reg], 1e-30f);
#pragma unroll
    for (int nt = 0; nt < 4; ++nt) {
      float v = cacc[nt][reg] * inv + b1v[nt];
      v = v > 0.f ? v : expm1f(v);
      sm.ob[jl][nt * 16 + m] = bf16_rn(v);
    }
  }
  __syncthreads();

  unsigned* go = hgl + (size_t)bt * 32768 + (size_t)z * 128 * 128 + head * 32;
#pragma unroll
  for (int c = 0; c < 2; ++c) {
    const int idx = tid * 2 + c;
    const int jl = idx >> 3, c4 = (idx & 7) * 4;
    *reinterpret_cast<uint4*>(&go[(size_t)jl * 128 + c4]) =
        *reinterpret_cast<const uint4*>(&sm.ob[jl][c4 * 2]);
  }
}

// ---------------------------------------------------------------------------
// Kernel 3: fused feat2+agg2. CHANGE (r12): grid (96, 4 j-quarters) x 256 thr
// (384 blocks, all CUs active; was 192). Wave covers 64 n in phase A,
// 16 j in phase B. es/ed via register q-reduction. K-chunk order preserved.
// ---------------------------------------------------------------------------
__global__ __launch_bounds__(256, 2) void fused2_kernel(
    const unsigned* __restrict__ hglu, const unsigned* __restrict__ W2Tu,
    const unsigned* __restrict__ mbg, const float* __restrict__ a2s,
    const float* __restrict__ a2d, const float* __restrict__ b2,
    const unsigned* __restrict__ WoTu, const float* __restrict__ spW,
    const float* __restrict__ tW, float* __restrict__ out) {
  const int bt = blockIdx.x, jh = blockIdx.y, tid = threadIdx.x;
  const int jbase = jh * 64;
  __shared__ union U {
    struct { unsigned h_c[256][36]; unsigned w2t_c[64][36]; } fs;  // 46080 B
    unsigned hpT[64][132];                                         // 33792 B
    unsigned short ob[64][72];                                     // 9216 B
  } sm;
  __shared__ unsigned wol[64][36];
  __shared__ unsigned mbs[512];       // 8 w-words x 64 j
  __shared__ float ess[256], eds[64];
  __shared__ float a2sv[64], a2dv[64];

  // persistent staging (ordered before use by first kc barrier)
#pragma unroll
  for (int c = 0; c < 2; ++c) {
    int idx = tid * 2 + c;
    int row = idx >> 3, col = (idx & 7) * 4;
    *reinterpret_cast<uint4*>(&wol[row][col]) =
        *reinterpret_cast<const uint4*>(&WoTu[row * 32 + col]);
  }
  if (tid < 128) {
    int w = tid >> 4, col = (tid & 15) * 4;
    *reinterpret_cast<uint4*>(&mbs[w * 64 + col]) =
        *reinterpret_cast<const uint4*>(&mbg[(size_t)bt * 2048 + w * 256 + jbase + col]);
  } else if (tid < 192) {
    a2sv[tid - 128] = a2s[tid - 128];
  } else {
    a2dv[tid - 192] = a2d[tid - 192];
  }

  const int lane = tid & 63, wv = tid >> 6;
  const int m = lane & 15, q = lane >> 4;
  const f32x4 z4 = {0.f, 0.f, 0.f, 0.f};

  // ---- Phase A: hp2 = W2T @ h; wave wv covers n in [wv*64, +64) ----
  f32x4 cf[4][4];
#pragma unroll
  for (int mt = 0; mt < 4; ++mt)
#pragma unroll
    for (int nt = 0; nt < 4; ++nt) cf[mt][nt] = z4;

  for (int kc = 0; kc < 4; ++kc) {
    __syncthreads();   // prior chunk reads (or persistent staging) done
#pragma unroll
    for (int c = 0; c < 8; ++c) {
      int i4 = tid + c * 256;
      int n = i4 >> 3, col = (i4 & 7) * 4;
      *reinterpret_cast<uint4*>(&sm.fs.h_c[n][col]) =
          *reinterpret_cast<const uint4*>(&hglu[(size_t)bt * 32768 + n * 128 + kc * 32 + col]);
    }
#pragma unroll
    for (int c = 0; c < 2; ++c) {
      int idx = tid * 2 + c;
      int d = idx >> 3, col = (idx & 7) * 4;
      *reinterpret_cast<uint4*>(&sm.fs.w2t_c[d][col]) =
          *reinterpret_cast<const uint4*>(&W2Tu[d * 128 + kc * 32 + col]);
    }
    __syncthreads();
#pragma unroll
    for (int kt2 = 0; kt2 < 2; ++kt2) {
      short8 af[4], bf[4];
#pragma unroll
      for (int mt = 0; mt < 4; ++mt)
        af[mt] = *reinterpret_cast<const short8*>(&sm.fs.w2t_c[mt * 16 + m][kt2 * 16 + q * 4]);
#pragma unroll
      for (int nt = 0; nt < 4; ++nt)
        bf[nt] = *reinterpret_cast<const short8*>(&sm.fs.h_c[wv * 64 + nt * 16 + m][kt2 * 16 + q * 4]);
#pragma unroll
      for (int mt = 0; mt < 4; ++mt)
#pragma unroll
        for (int nt = 0; nt < 4; ++nt)
          cf[mt][nt] = __builtin_amdgcn_mfma_f32_16x16x32_bf16(af[mt], bf[nt], cf[mt][nt], 0, 0, 0);
    }
  }
  __syncthreads();   // fs dead -> hpT overlay safe

  // ---- es/ed from cf registers + q-reduction ----
  {
    float pes[4] = {0.f, 0.f, 0.f, 0.f}, ped[4] = {0.f, 0.f, 0.f, 0.f};
#pragma unroll
    for (int mt = 0; mt < 4; ++mt)
#pragma unroll
      for (int reg = 0; reg < 4; ++reg) {
        const int d = mt * 16 + q * 4 + reg;
        const float a = a2sv[d], bdv = a2dv[d];
#pragma unroll
        for (int nt = 0; nt < 4; ++nt) {
          pes[nt] += cf[mt][nt][reg] * a;
          ped[nt] += cf[mt][nt][reg] * bdv;
        }
      }
#pragma unroll
    for (int nt = 0; nt < 4; ++nt) {
      pes[nt] += __shfl_xor(pes[nt], 16, 64); pes[nt] += __shfl_xor(pes[nt], 32, 64);
      ped[nt] += __shfl_xor(ped[nt], 16, 64); ped[nt] += __shfl_xor(ped[nt], 32, 64);
    }
    if (q == 0) {
#pragma unroll
      for (int nt = 0; nt < 4; ++nt) {
        const int n = wv * 64 + nt * 16 + m;
        ess[n] = pes[nt] * LOG2E;
        if (n >= jbase && n < jbase + 64) eds[n - jbase] = ped[nt] * LOG2E;
      }
    }
  }

  {
    unsigned short* hpT16 = reinterpret_cast<unsigned short*>(&sm.hpT[0][0]);
#pragma unroll
    for (int mt = 0; mt < 4; ++mt)
#pragma unroll
      for (int nt = 0; nt < 4; ++nt)
#pragma unroll
        for (int reg = 0; reg < 4; ++reg) {
          const int d = mt * 16 + q * 4 + reg;
          const int n = wv * 64 + nt * 16 + m;
          hpT16[d * 264 + n] = bf16_rn(cf[mt][nt][reg]);
        }
  }
  __syncthreads();

  // ---- Phase B: agg; wave owns 16 j-rows ----
  f32x4 cacc[4], cden = z4;
#pragma unroll
  for (int nt = 0; nt < 4; ++nt) cacc[nt] = z4;
  const float edv = eds[wv * 16 + m];
  const short8 ones8 = {(short)0x3F80, (short)0x3F80, (short)0x3F80, (short)0x3F80,
                        (short)0x3F80, (short)0x3F80, (short)0x3F80, (short)0x3F80};

  for (int kt = 0; kt < 8; ++kt) {
    short8 bfr[4];
#pragma unroll
    for (int nt = 0; nt < 4; ++nt)
      bfr[nt] = *reinterpret_cast<const short8*>(&sm.hpT[nt * 16 + m][kt * 16 + q * 4]);
    float e[8];
    *reinterpret_cast<float4*>(&e[0]) = *reinterpret_cast<const float4*>(&ess[kt * 32 + q * 8]);
    *reinterpret_cast<float4*>(&e[4]) = *reinterpret_cast<const float4*>(&ess[kt * 32 + q * 8 + 4]);
    const unsigned bits = mbs[kt * 64 + wv * 16 + m] >> (q * 8);
    float pv[8];
#pragma unroll
    for (int r = 0; r < 8; ++r) {
      float sc = e[r] + edv;
      sc = fmaxf(sc, 0.2f * sc);
      pv[r] = ((bits >> r) & 1u) ? exp2f(sc) : 0.f;
    }
    union { unsigned u[4]; short8 s; } A;
#pragma unroll
    for (int h = 0; h < 4; ++h) A.u[h] = pack_bf16x2(pv[2 * h], pv[2 * h + 1]);
#pragma unroll
    for (int nt = 0; nt < 4; ++nt)
      cacc[nt] = __builtin_amdgcn_mfma_f32_16x16x32_bf16(A.s, bfr[nt], cacc[nt], 0, 0, 0);
    cden = __builtin_amdgcn_mfma_f32_16x16x32_bf16(A.s, ones8, cden, 0, 0, 0);
  }
  __syncthreads();   // hpT dead -> ob overlay safe

  float b2v[4];
#pragma unroll
  for (int nt = 0; nt < 4; ++nt) b2v[nt] = b2[nt * 16 + m];
#pragma unroll
  for (int reg = 0; reg < 4; ++reg) {
    const int jl = wv * 16 + q * 4 + reg;
    const float inv = 1.f / fmaxf(cden[reg], 1e-30f);
#pragma unroll
    for (int nt = 0; nt < 4; ++nt)
      sm.ob[jl][nt * 16 + m] = bf16_rn(cacc[nt][reg] * inv + b2v[nt]);
  }
  __syncthreads();

  // ---- epilogue: out = od @ Wout[0:64] + spW + tW ----
  f32x4 c2[4];
#pragma unroll
  for (int ct = 0; ct < 4; ++ct) c2[ct] = z4;
#pragma unroll
  for (int kt2 = 0; kt2 < 2; ++kt2) {
    short8 a2f = *reinterpret_cast<const short8*>(&sm.ob[wv * 16 + m][kt2 * 32 + q * 8]);
#pragma unroll
    for (int ct = 0; ct < 4; ++ct) {
      short8 bw = *reinterpret_cast<const short8*>(&wol[ct * 16 + m][kt2 * 16 + q * 4]);
      c2[ct] = __builtin_amdgcn_mfma_f32_16x16x32_bf16(a2f, bw, c2[ct], 0, 0, 0);
    }
  }
  float tWv[4];
#pragma unroll
  for (int ct = 0; ct < 4; ++ct) tWv[ct] = tW[bt * 64 + ct * 16 + m];
#pragma unroll
  for (int reg = 0; reg < 4; ++reg) {
    const int j = jbase + wv * 16 + q * 4 + reg;
#pragma unroll
    for (int ct = 0; ct < 4; ++ct) {
      const int cc = ct * 16 + m;
      out[((size_t)bt * NNODE + j) * 64 + cc] =
          c2[ct][reg] + spW[j * 64 + cc] + tWv[ct];
    }
  }
}

// ---------------------------------------------------------------------------
extern "C" void kernel_launch(void* const* d_in, const int* in_sizes, int n_in,
                              void* d_out, int out_size, void* d_ws, size_t ws_size,
                              hipStream_t stream) {
  const float* x    = (const float*)d_in[0];
  const int*   adj  = (const int*)d_in[1];
  const float* te   = (const float*)d_in[2];
  const float* se   = (const float*)d_in[3];
  const float* pe   = (const float*)d_in[4];
  const float* Wt   = (const float*)d_in[5];
  const float* bt_  = (const float*)d_in[6];
  const float* Ws   = (const float*)d_in[7];
  const float* bs_  = (const float*)d_in[8];
  const float* Wp   = (const float*)d_in[9];
  const float* bp_  = (const float*)d_in[10];
  const float* Wfc  = (const float*)d_in[11];
  const float* bfc  = (const float*)d_in[12];
  const float* Wout = (const float*)d_in[13];
  const float* bout = (const float*)d_in[14];
  const float* W1   = (const float*)d_in[15];
  const float* b1   = (const float*)d_in[16];
  const float* a1s  = (const float*)d_in[17];
  const float* a1d  = (const float*)d_in[18];
  const float* W2   = (const float*)d_in[19];
  const float* b2   = (const float*)d_in[20];
  const float* a2s  = (const float*)d_in[21];
  const float* a2d  = (const float*)d_in[22];

  // workspace layout (offsets preserved)
  char* ws = (char*)d_ws;
  unsigned*       mb   = (unsigned*)(ws);                  // 786432
  float*          tW   = (float*)(ws + 786432);            // 24576
  float*          spW  = (float*)(ws + 811008);            // 65536
  unsigned short* WoT  = (unsigned short*)(ws + 876544);   // 8192
  unsigned short* W1T  = (unsigned short*)(ws + 884736);   // 32768
  unsigned short* W2T  = (unsigned short*)(ws + 917504);   // 32768
  unsigned*       hgl  = (unsigned*)(ws + 13533184);       // 12582912

  setup_kernel<<<1122, 256, 0, stream>>>(adj, mb, te, se, pe, Wt, bt_, Ws, bs_,
                                         Wp, bp_, Wfc, bfc, Wout, bout, W1, W2,
                                         tW, spW, WoT, W1T, W2T);
  fused1_kernel<<<dim3(NBT, 4, 2), 512, 0, stream>>>(x, (const unsigned*)W1T, mb,
                                                     a1s, a1d, b1, hgl);
  fused2_kernel<<<dim3(NBT, 4), 256, 0, stream>>>(hgl, (const unsigned*)W2T, mb,
                                                  a2s, a2d, b2, (const unsigned*)WoT,
                                                  spW, tW, (float*)d_out);
}